// Round 10
// baseline (350.109 us; speedup 1.0000x reference)
//
#include <hip/hip_runtime.h>

#define EPSV 1e-5f

typedef unsigned short u16;
typedef unsigned int u32;
typedef __attribute__((ext_vector_type(8))) short bf16x8;
typedef __attribute__((ext_vector_type(4))) float f32x4;

__device__ __forceinline__ u16 f2bf(float f) {
  u32 u = __float_as_uint(f);
  u32 r = (u + 0x7FFFu + ((u >> 16) & 1u)) >> 16;
  return (u16)r;
}
__device__ __forceinline__ float fexp2(float x) {
  float r;
  asm("v_exp_f32 %0, %1" : "=v"(r) : "v"(x));
  return r;
}

#define MFMA(a, b, c) __builtin_amdgcn_mfma_f32_16x16x32_bf16((a), (b), (c), 0, 0, 0)

// ---------------------------------------------------------------------------
// prep (fused): blocks 0..511 transpose x -> xT bf16 [(c>>4)][s][c&15];
// blocks 512..1791 cast weights (QSCALE*log2e folded into Wq rows).
// ---------------------------------------------------------------------------
__global__ __launch_bounds__(256) void prep_kernel(
    const float* __restrict__ x, const float* __restrict__ wqkv,
    const float* __restrict__ wproj, const float* __restrict__ wloc,
    u16* __restrict__ xT, u16* __restrict__ wqkvb,
    u16* __restrict__ wprojb, u16* __restrict__ wb) {
  __shared__ float Ls[16][260];
  const int bid = blockIdx.x;
  const int tid = threadIdx.x;
  if (bid < 512) {
    const int nt = bid & 15, cb = (bid >> 4) & 15, b = bid >> 8;
    const int cc0 = tid >> 6, n4 = (tid & 63) * 4;
    const float* xb = x + ((size_t)(b * 256 + cb * 16)) * 4096 + nt * 256;
#pragma unroll
    for (int j = 0; j < 4; j++) {
      int cc = j * 4 + cc0;
      *(float4*)&Ls[cc][n4] = *(const float4*)(xb + (size_t)cc * 4096 + n4);
    }
    __syncthreads();
    const int n = tid;
    u16 buf[16];
#pragma unroll
    for (int c = 0; c < 16; c++) buf[c] = f2bf(Ls[c][n]);
    u16* dst = xT + ((size_t)cb * 8192 + b * 4096 + nt * 256 + n) * 16;
    *(uint4*)(dst) = *(uint4*)&buf[0];
    *(uint4*)(dst + 8) = *(uint4*)&buf[8];
  } else {
    const int r = bid - 512, c = tid;
    const float QSCALE = 0.17677669529663687f * 1.4426950408889634f;
    if (r < 768) {
      float sc = (r < 256) ? QSCALE : 1.0f;
      wqkvb[r * 256 + c] = f2bf(wqkv[r * 256 + c] * sc);
    } else if (r < 1024) {
      int o = r - 768;
      wprojb[o * 256 + c] = f2bf(wproj[o * 256 + c]);
    } else {
      int o = r - 1024;
      const float* src = wloc + ((size_t)o * 256 + c) * 9;
#pragma unroll
      for (int tap = 0; tap < 9; tap++)
        wb[tap * 65536 + o * 256 + c] = f2bf(src[tap]);
    }
  }
}

// ---------------------------------------------------------------------------
// qkv GEMM (R7 fat tile, standalone): wave 32o x 64n, direct-from-L2.
// grid 768 = 64 n-tiles(128) x 12 o-tiles(64).
// ---------------------------------------------------------------------------
__global__ __launch_bounds__(256, 4) void qkv_kernel(
    const u16* __restrict__ xT, const u16* __restrict__ wqkvb,
    u16* __restrict__ Qg, u16* __restrict__ Kg, u16* __restrict__ Vtg) {
  const int bid = blockIdx.x;
  const int tid = threadIdx.x, lane = tid & 63, wv = tid >> 6;
  const int n16 = lane & 15, G = lane >> 4;
  const int nB = (bid & 63) * 128;
  const int oB = (bid >> 6) * 64;
  const int waveO = oB + (wv >> 1) * 32;
  const int waveN = nB + (wv & 1) * 64;
  f32x4 acc[2][4] = {};
  const u16* Ap = wqkvb + (size_t)(waveO + n16) * 256 + G * 8;
  const u16* Bp = xT + ((size_t)(G >> 1) * 8192 + waveN + n16) * 16 + (G & 1) * 8;
  for (int c0 = 0; c0 < 256; c0 += 32) {
    bf16x8 a0 = *(const bf16x8*)(Ap + c0);
    bf16x8 a1 = *(const bf16x8*)(Ap + 16 * 256 + c0);
    const u16* bp = Bp + (size_t)(c0 >> 4) * 131072;
    bf16x8 b0 = *(const bf16x8*)(bp);
    bf16x8 b1 = *(const bf16x8*)(bp + 256);
    bf16x8 b2 = *(const bf16x8*)(bp + 512);
    bf16x8 b3 = *(const bf16x8*)(bp + 768);
    acc[0][0] = MFMA(a0, b0, acc[0][0]);
    acc[0][1] = MFMA(a0, b1, acc[0][1]);
    acc[0][2] = MFMA(a0, b2, acc[0][2]);
    acc[0][3] = MFMA(a0, b3, acc[0][3]);
    acc[1][0] = MFMA(a1, b0, acc[1][0]);
    acc[1][1] = MFMA(a1, b1, acc[1][1]);
    acc[1][2] = MFMA(a1, b2, acc[1][2]);
    acc[1][3] = MFMA(a1, b3, acc[1][3]);
  }
  const int which = oB >> 8;
  if (which < 2) {
    u16* base = which ? Kg : Qg;
#pragma unroll
    for (int i = 0; i < 2; i++) {
      int o0 = waveO + i * 16 + G * 4;
      int h = (o0 >> 5) & 7, d0 = o0 & 31;
#pragma unroll
      for (int j = 0; j < 4; j++) {
        int s = waveN + j * 16 + n16;
        int b = s >> 12, n = s & 4095;
        u16 pk[4];
#pragma unroll
        for (int r = 0; r < 4; r++) pk[r] = f2bf(acc[i][j][r]);
        *(uint2*)(base + ((size_t)(b * 8 + h) * 4096 + n) * 32 + d0) = *(uint2*)pk;
      }
    }
  } else {
#pragma unroll
    for (int i = 0; i < 2; i++) {
      int o0 = waveO + i * 16 + G * 4;
      int h = (o0 >> 5) & 7, d0 = o0 & 31;
#pragma unroll
      for (int j = 0; j < 4; j++) {
        int s = waveN + j * 16 + n16;
        int b = s >> 12, n = s & 4095;
        u16* vp = Vtg + ((size_t)(b * 8 + h) * 32 + d0) * 4096 + n;
#pragma unroll
        for (int r = 0; r < 4; r++) vp[(size_t)r * 4096] = f2bf(acc[i][j][r]);
      }
    }
  }
}

// ---------------------------------------------------------------------------
// flashconv (fused): grid 2560. bid%5==4 -> conv3x3+BN (512 blocks, R7 code,
// MFMA/L2-heavy); else flash m-split-4 (2048 blocks, VALU-heavy) -- the two
// block types co-schedule on a CU and fill each other's pipe bubbles.
// flash: block = 4 waves on one 32-q group; wave w covers m [w*1024,+1024).
// Max-tracked softmax (proven), VALU per-lane l (R7), K prefetch, 4-way merge
// via MX overlaid on Ps (18KB LDS). __launch_bounds__(256,5): 102-reg budget
// vs ~75 peak -- NO spill (R8/R9 lesson: budget is unified VGPR+AGPR).
// ---------------------------------------------------------------------------
__global__ __launch_bounds__(256, 5) void flashconv_kernel(
    const u16* __restrict__ Qg, const u16* __restrict__ Kg,
    const u16* __restrict__ Vtg, u16* __restrict__ attnT,
    const u16* __restrict__ xT, const u16* __restrict__ wb,
    const float* __restrict__ g, const float* __restrict__ be,
    const float* __restrict__ mu, const float* __restrict__ var,
    u16* __restrict__ localT) {
  __shared__ u32 SMEM[4608];          // 18432 B: Ps (4x1152) overlaid by MX
  const int bid = blockIdx.x;
  const int tid = threadIdx.x, lane = tid & 63;
  const int n16 = lane & 15, G = lane >> 4;
  const int sel = bid % 5;
  if (sel == 4) {
    // ---------------- conv3x3 + BN (R7) ----------------
    const int cidx = bid / 5;                // 0..511
    const int wv = tid >> 6;
    const int nB = (cidx & 127) * 64;
    const int oB = (cidx >> 7) * 64;
    const int waveO = oB + (wv >> 1) * 32;
    const int waveN = nB + (wv & 1) * 32;
    const int y = (nB >> 6) & 63;
    const int x0 = waveN & 63;
    f32x4 acc[2][2] = {};
    const u16* Ap = wb + (size_t)(waveO + n16) * 256 + G * 8;
    const u16* Bp = xT + ((size_t)(G >> 1) * 8192 + waveN + n16) * 16 + (G & 1) * 8;
    const bf16x8 z = {0, 0, 0, 0, 0, 0, 0, 0};
    for (int c0 = 0; c0 < 256; c0 += 32) {
      const u16* bp = Bp + (size_t)(c0 >> 4) * 131072;
      const u16* ap = Ap + c0;
#pragma unroll
      for (int tap = 0; tap < 9; tap++) {
        const int dy = tap / 3 - 1, dx = tap % 3 - 1;
        int yy = y + dy;
        if ((unsigned)yy >= 64u) continue;
        bf16x8 a0 = *(const bf16x8*)(ap + (size_t)tap * 65536);
        bf16x8 a1 = *(const bf16x8*)(ap + (size_t)tap * 65536 + 16 * 256);
        const int off = dy * 64 + dx;
        bf16x8 b0, b1;
        if (dx == 0) {
          b0 = *(const bf16x8*)(bp + (ptrdiff_t)off * 16);
          b1 = *(const bf16x8*)(bp + (ptrdiff_t)(off + 16) * 16);
        } else {
          bool v0 = (unsigned)(x0 + n16 + dx) < 64u;
          bool v1 = (unsigned)(x0 + 16 + n16 + dx) < 64u;
          int o0 = v0 ? off : 0;
          int o1 = v1 ? (off + 16) : 16;
          bf16x8 t0 = *(const bf16x8*)(bp + (ptrdiff_t)o0 * 16);
          bf16x8 t1 = *(const bf16x8*)(bp + (ptrdiff_t)o1 * 16);
          b0 = v0 ? t0 : z;
          b1 = v1 ? t1 : z;
        }
        acc[0][0] = MFMA(a0, b0, acc[0][0]);
        acc[0][1] = MFMA(a0, b1, acc[0][1]);
        acc[1][0] = MFMA(a1, b0, acc[1][0]);
        acc[1][1] = MFMA(a1, b1, acc[1][1]);
      }
    }
#pragma unroll
    for (int i = 0; i < 2; i++) {
      int o0 = waveO + i * 16 + G * 4;
      float inv[4], sh[4];
#pragma unroll
      for (int r = 0; r < 4; r++) {
        int o = o0 + r;
        float iv = g[o] * rsqrtf(var[o] + EPSV);
        inv[r] = iv; sh[r] = be[o] - mu[o] * iv;
      }
#pragma unroll
      for (int j = 0; j < 2; j++) {
        int s = waveN + j * 16 + n16;
        u16 pk[4];
#pragma unroll
        for (int r = 0; r < 4; r++) pk[r] = f2bf(acc[i][j][r] * inv[r] + sh[r]);
        *(uint2*)(localT + ((size_t)(o0 >> 4) * 8192 + s) * 16 + (o0 & 15)) = *(uint2*)pk;
      }
    }
    return;
  }

  // ---------------- flash, m-split 4 ----------------
  const int fidx = (bid / 5) * 4 + sel;      // 0..2047
  const int bh = fidx >> 7, qt = fidx & 127;
  const int w = tid >> 6;
  const int b = bh >> 3, h = bh & 7;
  const int qbase = qt * 32;

  const u16* Qp = Qg + ((size_t)bh * 4096 + qbase) * 32;
  const bf16x8 qf0 = *(const bf16x8*)(Qp + (size_t)n16 * 32 + G * 8);
  const bf16x8 qf1 = *(const bf16x8*)(Qp + (size_t)(16 + n16) * 32 + G * 8);

  f32x4 O00 = {0.f,0.f,0.f,0.f}, O01 = {0.f,0.f,0.f,0.f};
  f32x4 O10 = {0.f,0.f,0.f,0.f}, O11 = {0.f,0.f,0.f,0.f};
  float m0 = -3.0e38f, m1 = -3.0e38f, l0 = 0.f, l1 = 0.f;

  const u16* Kb = Kg + ((size_t)bh * 4096 + w * 1024) * 32;
  const u16* Vb = Vtg + (size_t)bh * 32 * 4096 + w * 1024;
  u32* Pw = SMEM + w * 1152;

  bf16x8 kf0 = *(const bf16x8*)(Kb + (size_t)n16 * 32 + G * 8);
  bf16x8 kf1 = *(const bf16x8*)(Kb + (size_t)(16 + n16) * 32 + G * 8);
  bf16x8 kf2 = *(const bf16x8*)(Kb + (size_t)(32 + n16) * 32 + G * 8);
  bf16x8 kf3 = *(const bf16x8*)(Kb + (size_t)(48 + n16) * 32 + G * 8);

  for (int it = 0; it < 16; ++it) {
    const f32x4 z = {0.f, 0.f, 0.f, 0.f};
    f32x4 S0[4], S1[4];
    S0[0] = MFMA(kf0, qf0, z); S1[0] = MFMA(kf0, qf1, z);
    S0[1] = MFMA(kf1, qf0, z); S1[1] = MFMA(kf1, qf1, z);
    S0[2] = MFMA(kf2, qf0, z); S1[2] = MFMA(kf2, qf1, z);
    S0[3] = MFMA(kf3, qf0, z); S1[3] = MFMA(kf3, qf1, z);

    {
      const u16* Kn = Kb + (size_t)(((it + 1) & 15) * 64) * 32;
      kf0 = *(const bf16x8*)(Kn + (size_t)n16 * 32 + G * 8);
      kf1 = *(const bf16x8*)(Kn + (size_t)(16 + n16) * 32 + G * 8);
      kf2 = *(const bf16x8*)(Kn + (size_t)(32 + n16) * 32 + G * 8);
      kf3 = *(const bf16x8*)(Kn + (size_t)(48 + n16) * 32 + G * 8);
    }

    float mt0 = fmaxf(fmaxf(S0[0].x, S0[0].y), fmaxf(S0[0].z, S0[0].w));
    float mt1 = fmaxf(fmaxf(S1[0].x, S1[0].y), fmaxf(S1[0].z, S1[0].w));
#pragma unroll
    for (int t = 1; t < 4; t++) {
      mt0 = fmaxf(mt0, fmaxf(fmaxf(S0[t].x, S0[t].y), fmaxf(S0[t].z, S0[t].w)));
      mt1 = fmaxf(mt1, fmaxf(fmaxf(S1[t].x, S1[t].y), fmaxf(S1[t].z, S1[t].w)));
    }
    mt0 = fmaxf(mt0, __shfl_xor(mt0, 16, 64));
    mt0 = fmaxf(mt0, __shfl_xor(mt0, 32, 64));
    mt1 = fmaxf(mt1, __shfl_xor(mt1, 16, 64));
    mt1 = fmaxf(mt1, __shfl_xor(mt1, 32, 64));
    float mn0 = fmaxf(m0, mt0), mn1 = fmaxf(m1, mt1);
    if (__any((mt0 > m0) | (mt1 > m1))) {
      float a0 = fexp2(m0 - mn0);
      float a1 = fexp2(m1 - mn1);
      l0 *= a0; l1 *= a1;
      O00 *= a0; O01 *= a0; O10 *= a1; O11 *= a1;
    }
    m0 = mn0; m1 = mn1;

#pragma unroll
    for (int t = 0; t < 4; t++) {
      float p0 = fexp2(S0[t].x - m0), p1 = fexp2(S0[t].y - m0);
      float p2 = fexp2(S0[t].z - m0), p3 = fexp2(S0[t].w - m0);
      l0 += (p0 + p1) + (p2 + p3);
      uint2 pr;
      pr.x = __builtin_amdgcn_perm(__float_as_uint(p1), __float_as_uint(p0), 0x07060302u);
      pr.y = __builtin_amdgcn_perm(__float_as_uint(p3), __float_as_uint(p2), 0x07060302u);
      *(uint2*)&Pw[n16 * 36 + 8 * t + 2 * G] = pr;
      float q0 = fexp2(S1[t].x - m1), q1 = fexp2(S1[t].y - m1);
      float q2 = fexp2(S1[t].z - m1), q3 = fexp2(S1[t].w - m1);
      l1 += (q0 + q1) + (q2 + q3);
      uint2 qr;
      qr.x = __builtin_amdgcn_perm(__float_as_uint(q1), __float_as_uint(q0), 0x07060302u);
      qr.y = __builtin_amdgcn_perm(__float_as_uint(q3), __float_as_uint(q2), 0x07060302u);
      *(uint2*)&Pw[(16 + n16) * 36 + 8 * t + 2 * G] = qr;
    }

#pragma unroll
    for (int c = 0; c < 2; c++) {
      const u16* Vp = Vb + (size_t)it * 64 + c * 32 + G * 8;
      bf16x8 va0 = *(const bf16x8*)(Vp + (size_t)n16 * 4096);
      bf16x8 va1 = *(const bf16x8*)(Vp + (size_t)(16 + n16) * 4096);
      union { uint4 u; bf16x8 v; } B0, B1;
      B0.u = *(uint4*)&Pw[n16 * 36 + 16 * c + 4 * G];
      B1.u = *(uint4*)&Pw[(16 + n16) * 36 + 16 * c + 4 * G];
      O00 = MFMA(va0, B0.v, O00);
      O01 = MFMA(va1, B0.v, O01);
      O10 = MFMA(va0, B1.v, O10);
      O11 = MFMA(va1, B1.v, O11);
    }
  }

  // -------- merge 4 m-split partials (MX overlays Ps; barriers) --------
  __syncthreads();
  float* MXf = (float*)SMEM;
  if (w > 0) {
    float* dst = MXf + ((size_t)(w - 1) * 64 + lane) * 20;
    *(f32x4*)(dst + 0)  = O00;
    *(f32x4*)(dst + 4)  = O01;
    *(f32x4*)(dst + 8)  = O10;
    *(f32x4*)(dst + 12) = O11;
    dst[16] = m0; dst[17] = l0; dst[18] = m1; dst[19] = l1;
  }
  __syncthreads();
  if (w == 0) {
    float M0 = m0, M1 = m1;
#pragma unroll
    for (int ww = 0; ww < 3; ww++) {
      const float* src = MXf + ((size_t)ww * 64 + lane) * 20;
      M0 = fmaxf(M0, src[16]);
      M1 = fmaxf(M1, src[18]);
    }
    float se0 = fexp2(m0 - M0), se1 = fexp2(m1 - M1);
    f32x4 A00 = O00 * se0, A01 = O01 * se0;
    f32x4 A10 = O10 * se1, A11 = O11 * se1;
    float l0s = l0 * se0, l1s = l1 * se1;
#pragma unroll
    for (int ww = 0; ww < 3; ww++) {
      const float* src = MXf + ((size_t)ww * 64 + lane) * 20;
      float s0 = fexp2(src[16] - M0), s1 = fexp2(src[18] - M1);
      A00 += *(const f32x4*)(src + 0) * s0;
      A01 += *(const f32x4*)(src + 4) * s0;
      A10 += *(const f32x4*)(src + 8) * s1;
      A11 += *(const f32x4*)(src + 12) * s1;
      l0s += src[17] * s0;
      l1s += src[19] * s1;
    }
    l0s += __shfl_xor(l0s, 16, 64);
    l0s += __shfl_xor(l0s, 32, 64);
    l1s += __shfl_xor(l1s, 16, 64);
    l1s += __shfl_xor(l1s, 32, 64);
    const float rl0 = 1.0f / l0s, rl1 = 1.0f / l1s;
    const int s0i = b * 4096 + qbase + n16;
    const int s1i = s0i + 16;
    const int cb0 = h * 2, cb1 = h * 2 + 1;
    u16 pk[4];
#pragma unroll
    for (int r = 0; r < 4; r++) pk[r] = f2bf(A00[r] * rl0);
    *(uint2*)(attnT + ((size_t)cb0 * 8192 + s0i) * 16 + G * 4) = *(uint2*)pk;
#pragma unroll
    for (int r = 0; r < 4; r++) pk[r] = f2bf(A01[r] * rl0);
    *(uint2*)(attnT + ((size_t)cb1 * 8192 + s0i) * 16 + G * 4) = *(uint2*)pk;
#pragma unroll
    for (int r = 0; r < 4; r++) pk[r] = f2bf(A10[r] * rl1);
    *(uint2*)(attnT + ((size_t)cb0 * 8192 + s1i) * 16 + G * 4) = *(uint2*)pk;
#pragma unroll
    for (int r = 0; r < 4; r++) pk[r] = f2bf(A11[r] * rl1);
    *(uint2*)(attnT + ((size_t)cb1 * 8192 + s1i) * 16 + G * 4) = *(uint2*)pk;
  }
}

// ---------------------------------------------------------------------------
// proj MFMA + BN (R7): wave = 32o x 32n, dual B-stream into one acc.
// ---------------------------------------------------------------------------
__global__ __launch_bounds__(256, 4) void proj_mfma_kernel(
    const u16* __restrict__ attnT, const u16* __restrict__ localT,
    const u16* __restrict__ wprojb,
    const float* __restrict__ g, const float* __restrict__ be,
    const float* __restrict__ mu, const float* __restrict__ var,
    float* __restrict__ out) {
  const int nB = blockIdx.x * 64;
  const int oB = blockIdx.y * 64;
  const int tid = threadIdx.x, lane = tid & 63, wv = tid >> 6;
  const int n16 = lane & 15, G = lane >> 4;
  const int waveO = oB + (wv >> 1) * 32;
  const int waveN = nB + (wv & 1) * 32;
  f32x4 acc[2][2] = {};
  const u16* Ap = wprojb + (size_t)(waveO + n16) * 256 + G * 8;
  const size_t boff = ((size_t)(G >> 1) * 8192 + waveN + n16) * 16 + (G & 1) * 8;
  for (int c0 = 0; c0 < 256; c0 += 32) {
    bf16x8 a0 = *(const bf16x8*)(Ap + c0);
    bf16x8 a1 = *(const bf16x8*)(Ap + 16 * 256 + c0);
    const size_t bo = boff + (size_t)(c0 >> 4) * 131072;
    bf16x8 p0 = *(const bf16x8*)(attnT + bo);
    bf16x8 p1 = *(const bf16x8*)(attnT + bo + 256);
    bf16x8 q0 = *(const bf16x8*)(localT + bo);
    bf16x8 q1 = *(const bf16x8*)(localT + bo + 256);
    acc[0][0] = MFMA(a0, p0, acc[0][0]);
    acc[0][1] = MFMA(a0, p1, acc[0][1]);
    acc[1][0] = MFMA(a1, p0, acc[1][0]);
    acc[1][1] = MFMA(a1, p1, acc[1][1]);
    acc[0][0] = MFMA(a0, q0, acc[0][0]);
    acc[0][1] = MFMA(a0, q1, acc[0][1]);
    acc[1][0] = MFMA(a1, q0, acc[1][0]);
    acc[1][1] = MFMA(a1, q1, acc[1][1]);
  }
#pragma unroll
  for (int i = 0; i < 2; i++) {
    int o0 = waveO + i * 16 + G * 4;
    float inv[4], sh[4];
#pragma unroll
    for (int r = 0; r < 4; r++) {
      int o = o0 + r;
      float iv = g[o] * rsqrtf(var[o] + EPSV);
      inv[r] = iv; sh[r] = be[o] - mu[o] * iv;
    }
#pragma unroll
    for (int j = 0; j < 2; j++) {
      int s = waveN + j * 16 + n16;
      int b = s >> 12, n = s & 4095;
      float* op = out + ((size_t)(b * 256 + o0)) * 4096 + n;
#pragma unroll
      for (int r = 0; r < 4; r++) op[(size_t)r * 4096] = acc[i][j][r] * inv[r] + sh[r];
    }
  }
}

extern "C" void kernel_launch(void* const* d_in, const int* in_sizes, int n_in,
                              void* d_out, int out_size, void* d_ws, size_t ws_size,
                              hipStream_t stream) {
  (void)in_sizes; (void)n_in; (void)out_size; (void)ws_size;
  const float* x       = (const float*)d_in[0];
  const float* w_qkv   = (const float*)d_in[1];
  const float* w_local = (const float*)d_in[2];
  const float* lg = (const float*)d_in[3];
  const float* lb = (const float*)d_in[4];
  const float* lm = (const float*)d_in[5];
  const float* lv = (const float*)d_in[6];
  const float* w_proj  = (const float*)d_in[7];
  const float* pg = (const float*)d_in[8];
  const float* pb = (const float*)d_in[9];
  const float* pm = (const float*)d_in[10];
  const float* pvr = (const float*)d_in[11];
  float* out = (float*)d_out;

  // ws layout (u16 units)
  u16* Q      = (u16*)d_ws;          // 2M
  u16* K      = Q + 2097152;         // 2M
  u16* Vt     = K + 2097152;         // 2M
  u16* xT     = Vt + 2097152;        // 2M
  u16* attnT  = xT + 2097152;        // 2M
  u16* localT = attnT + 2097152;     // 2M
  u16* wqkvb  = localT + 2097152;    // 196608
  u16* wprojb = wqkvb + 196608;      // 65536
  u16* wb     = wprojb + 65536;      // 589824

  hipLaunchKernelGGL(prep_kernel, dim3(1792), dim3(256), 0, stream,
                     x, w_qkv, w_proj, w_local, xT, wqkvb, wprojb, wb);
  hipLaunchKernelGGL(qkv_kernel, dim3(768), dim3(256), 0, stream,
                     xT, wqkvb, Q, K, Vt);
  hipLaunchKernelGGL(flashconv_kernel, dim3(2560), dim3(256), 0, stream,
                     Q, K, Vt, attnT, xT, wb, lg, lb, lm, lv, localT);
  hipLaunchKernelGGL(proj_mfma_kernel, dim3(128, 4), dim3(256), 0, stream,
                     attnT, localT, wprojb, pg, pb, pm, pvr, out);
}

// Round 11
// 259.779 us; speedup vs baseline: 1.3477x; 1.3477x over previous
//
#include <hip/hip_runtime.h>

#define EPSV 1e-5f

typedef unsigned short u16;
typedef unsigned int u32;
typedef __attribute__((ext_vector_type(8))) short bf16x8;
typedef __attribute__((ext_vector_type(4))) float f32x4;

__device__ __forceinline__ u16 f2bf(float f) {
  u32 u = __float_as_uint(f);
  u32 r = (u + 0x7FFFu + ((u >> 16) & 1u)) >> 16;
  return (u16)r;
}
__device__ __forceinline__ float fexp2(float x) {
  float r;
  asm("v_exp_f32 %0, %1" : "=v"(r) : "v"(x));
  return r;
}

#define MFMA(a, b, c) __builtin_amdgcn_mfma_f32_16x16x32_bf16((a), (b), (c), 0, 0, 0)

// ---------------------------------------------------------------------------
// prep (fused): blocks 0..511 transpose x -> xT bf16 [(c>>4)][s][c&15];
// blocks 512..1791 cast weights (QSCALE*log2e folded into Wq rows).
// ---------------------------------------------------------------------------
__global__ __launch_bounds__(256) void prep_kernel(
    const float* __restrict__ x, const float* __restrict__ wqkv,
    const float* __restrict__ wproj, const float* __restrict__ wloc,
    u16* __restrict__ xT, u16* __restrict__ wqkvb,
    u16* __restrict__ wprojb, u16* __restrict__ wb) {
  __shared__ float Ls[16][260];
  const int bid = blockIdx.x;
  const int tid = threadIdx.x;
  if (bid < 512) {
    const int nt = bid & 15, cb = (bid >> 4) & 15, b = bid >> 8;
    const int cc0 = tid >> 6, n4 = (tid & 63) * 4;
    const float* xb = x + ((size_t)(b * 256 + cb * 16)) * 4096 + nt * 256;
#pragma unroll
    for (int j = 0; j < 4; j++) {
      int cc = j * 4 + cc0;
      *(float4*)&Ls[cc][n4] = *(const float4*)(xb + (size_t)cc * 4096 + n4);
    }
    __syncthreads();
    const int n = tid;
    u16 buf[16];
#pragma unroll
    for (int c = 0; c < 16; c++) buf[c] = f2bf(Ls[c][n]);
    u16* dst = xT + ((size_t)cb * 8192 + b * 4096 + nt * 256 + n) * 16;
    *(uint4*)(dst) = *(uint4*)&buf[0];
    *(uint4*)(dst + 8) = *(uint4*)&buf[8];
  } else {
    const int r = bid - 512, c = tid;
    const float QSCALE = 0.17677669529663687f * 1.4426950408889634f;
    if (r < 768) {
      float sc = (r < 256) ? QSCALE : 1.0f;
      wqkvb[r * 256 + c] = f2bf(wqkv[r * 256 + c] * sc);
    } else if (r < 1024) {
      int o = r - 768;
      wprojb[o * 256 + c] = f2bf(wproj[o * 256 + c]);
    } else {
      int o = r - 1024;
      const float* src = wloc + ((size_t)o * 256 + c) * 9;
#pragma unroll
      for (int tap = 0; tap < 9; tap++)
        wb[tap * 65536 + o * 256 + c] = f2bf(src[tap]);
    }
  }
}

// ---------------------------------------------------------------------------
// qkv GEMM (R7 fat tile): wave 32o x 64n, direct-from-L2. grid 768.
// ---------------------------------------------------------------------------
__global__ __launch_bounds__(256, 4) void qkv_kernel(
    const u16* __restrict__ xT, const u16* __restrict__ wqkvb,
    u16* __restrict__ Qg, u16* __restrict__ Kg, u16* __restrict__ Vtg) {
  const int bid = blockIdx.x;
  const int tid = threadIdx.x, lane = tid & 63, wv = tid >> 6;
  const int n16 = lane & 15, G = lane >> 4;
  const int nB = (bid & 63) * 128;
  const int oB = (bid >> 6) * 64;
  const int waveO = oB + (wv >> 1) * 32;
  const int waveN = nB + (wv & 1) * 64;
  f32x4 acc[2][4] = {};
  const u16* Ap = wqkvb + (size_t)(waveO + n16) * 256 + G * 8;
  const u16* Bp = xT + ((size_t)(G >> 1) * 8192 + waveN + n16) * 16 + (G & 1) * 8;
  for (int c0 = 0; c0 < 256; c0 += 32) {
    bf16x8 a0 = *(const bf16x8*)(Ap + c0);
    bf16x8 a1 = *(const bf16x8*)(Ap + 16 * 256 + c0);
    const u16* bp = Bp + (size_t)(c0 >> 4) * 131072;
    bf16x8 b0 = *(const bf16x8*)(bp);
    bf16x8 b1 = *(const bf16x8*)(bp + 256);
    bf16x8 b2 = *(const bf16x8*)(bp + 512);
    bf16x8 b3 = *(const bf16x8*)(bp + 768);
    acc[0][0] = MFMA(a0, b0, acc[0][0]);
    acc[0][1] = MFMA(a0, b1, acc[0][1]);
    acc[0][2] = MFMA(a0, b2, acc[0][2]);
    acc[0][3] = MFMA(a0, b3, acc[0][3]);
    acc[1][0] = MFMA(a1, b0, acc[1][0]);
    acc[1][1] = MFMA(a1, b1, acc[1][1]);
    acc[1][2] = MFMA(a1, b2, acc[1][2]);
    acc[1][3] = MFMA(a1, b3, acc[1][3]);
  }
  const int which = oB >> 8;
  if (which < 2) {
    u16* base = which ? Kg : Qg;
#pragma unroll
    for (int i = 0; i < 2; i++) {
      int o0 = waveO + i * 16 + G * 4;
      int h = (o0 >> 5) & 7, d0 = o0 & 31;
#pragma unroll
      for (int j = 0; j < 4; j++) {
        int s = waveN + j * 16 + n16;
        int b = s >> 12, n = s & 4095;
        u16 pk[4];
#pragma unroll
        for (int r = 0; r < 4; r++) pk[r] = f2bf(acc[i][j][r]);
        *(uint2*)(base + ((size_t)(b * 8 + h) * 4096 + n) * 32 + d0) = *(uint2*)pk;
      }
    }
  } else {
#pragma unroll
    for (int i = 0; i < 2; i++) {
      int o0 = waveO + i * 16 + G * 4;
      int h = (o0 >> 5) & 7, d0 = o0 & 31;
#pragma unroll
      for (int j = 0; j < 4; j++) {
        int s = waveN + j * 16 + n16;
        int b = s >> 12, n = s & 4095;
        u16* vp = Vtg + ((size_t)(b * 8 + h) * 32 + d0) * 4096 + n;
#pragma unroll
        for (int r = 0; r < 4; r++) vp[(size_t)r * 4096] = f2bf(acc[i][j][r]);
      }
    }
  }
}

// ---------------------------------------------------------------------------
// flashconv: grid 1536, __launch_bounds__(256,4) (PROVEN no-spill budget).
// bid%3==2 -> conv3x3+BN (512 blocks, MFMA/L2-heavy);
// else     -> R7's exact m-split-2 flash (1024 blocks, VALU/latency-heavy).
// The two block types co-schedule per CU, filling each other's pipe bubbles.
// ---------------------------------------------------------------------------
__global__ __launch_bounds__(256, 4) void flashconv_kernel(
    const u16* __restrict__ Qg, const u16* __restrict__ Kg,
    const u16* __restrict__ Vtg, u16* __restrict__ attnT,
    const u16* __restrict__ xT, const u16* __restrict__ wb,
    const float* __restrict__ g, const float* __restrict__ be,
    const float* __restrict__ mu, const float* __restrict__ var,
    u16* __restrict__ localT) {
  __shared__ u32 Ps[4][32 * 36];
  __shared__ float MX[2][64][20];
  const int bid = blockIdx.x;
  const int tid = threadIdx.x, lane = tid & 63;
  const int n16 = lane & 15, G = lane >> 4;
  const int sel = bid % 3;

  if (sel == 2) {
    // ---------------- conv3x3 + BN (R7 exact) ----------------
    const int cidx = bid / 3;                // 0..511
    const int wv = tid >> 6;
    const int nB = (cidx & 127) * 64;
    const int oB = (cidx >> 7) * 64;
    const int waveO = oB + (wv >> 1) * 32;
    const int waveN = nB + (wv & 1) * 32;
    const int y = (nB >> 6) & 63;
    const int x0 = waveN & 63;
    f32x4 acc[2][2] = {};
    const u16* Ap = wb + (size_t)(waveO + n16) * 256 + G * 8;
    const u16* Bp = xT + ((size_t)(G >> 1) * 8192 + waveN + n16) * 16 + (G & 1) * 8;
    const bf16x8 z = {0, 0, 0, 0, 0, 0, 0, 0};
    for (int c0 = 0; c0 < 256; c0 += 32) {
      const u16* bp = Bp + (size_t)(c0 >> 4) * 131072;
      const u16* ap = Ap + c0;
#pragma unroll
      for (int tap = 0; tap < 9; tap++) {
        const int dy = tap / 3 - 1, dx = tap % 3 - 1;
        int yy = y + dy;
        if ((unsigned)yy >= 64u) continue;
        bf16x8 a0 = *(const bf16x8*)(ap + (size_t)tap * 65536);
        bf16x8 a1 = *(const bf16x8*)(ap + (size_t)tap * 65536 + 16 * 256);
        const int off = dy * 64 + dx;
        bf16x8 b0, b1;
        if (dx == 0) {
          b0 = *(const bf16x8*)(bp + (ptrdiff_t)off * 16);
          b1 = *(const bf16x8*)(bp + (ptrdiff_t)(off + 16) * 16);
        } else {
          bool v0 = (unsigned)(x0 + n16 + dx) < 64u;
          bool v1 = (unsigned)(x0 + 16 + n16 + dx) < 64u;
          int o0 = v0 ? off : 0;
          int o1 = v1 ? (off + 16) : 16;
          bf16x8 t0 = *(const bf16x8*)(bp + (ptrdiff_t)o0 * 16);
          bf16x8 t1 = *(const bf16x8*)(bp + (ptrdiff_t)o1 * 16);
          b0 = v0 ? t0 : z;
          b1 = v1 ? t1 : z;
        }
        acc[0][0] = MFMA(a0, b0, acc[0][0]);
        acc[0][1] = MFMA(a0, b1, acc[0][1]);
        acc[1][0] = MFMA(a1, b0, acc[1][0]);
        acc[1][1] = MFMA(a1, b1, acc[1][1]);
      }
    }
#pragma unroll
    for (int i = 0; i < 2; i++) {
      int o0 = waveO + i * 16 + G * 4;
      float inv[4], sh[4];
#pragma unroll
      for (int r = 0; r < 4; r++) {
        int o = o0 + r;
        float iv = g[o] * rsqrtf(var[o] + EPSV);
        inv[r] = iv; sh[r] = be[o] - mu[o] * iv;
      }
#pragma unroll
      for (int j = 0; j < 2; j++) {
        int s = waveN + j * 16 + n16;
        u16 pk[4];
#pragma unroll
        for (int r = 0; r < 4; r++) pk[r] = f2bf(acc[i][j][r] * inv[r] + sh[r]);
        *(uint2*)(localT + ((size_t)(o0 >> 4) * 8192 + s) * 16 + (o0 & 15)) = *(uint2*)pk;
      }
    }
    return;
  }

  // ---------------- flash, m-split 2 (R7 exact) ----------------
  const int fidx = (bid / 3) * 2 + sel;      // 0..1023
  const int bh = fidx >> 6, qt = fidx & 63;
  const int w = tid >> 6;
  const int gq = w >> 1, mh = w & 1;
  const int b = bh >> 3, h = bh & 7;
  const int qbase = qt * 64 + gq * 32;

  const u16* Qp = Qg + ((size_t)bh * 4096 + qbase) * 32;
  const bf16x8 qf0 = *(const bf16x8*)(Qp + (size_t)n16 * 32 + G * 8);
  const bf16x8 qf1 = *(const bf16x8*)(Qp + (size_t)(16 + n16) * 32 + G * 8);

  f32x4 O00 = {0.f,0.f,0.f,0.f}, O01 = {0.f,0.f,0.f,0.f};
  f32x4 O10 = {0.f,0.f,0.f,0.f}, O11 = {0.f,0.f,0.f,0.f};
  float m0 = -3.0e38f, m1 = -3.0e38f, l0 = 0.f, l1 = 0.f;

  const u16* Kb = Kg + ((size_t)bh * 4096 + mh * 2048) * 32;
  const u16* Vb = Vtg + (size_t)bh * 32 * 4096 + mh * 2048;
  u32* Pw = Ps[w];

  bf16x8 kf0 = *(const bf16x8*)(Kb + (size_t)n16 * 32 + G * 8);
  bf16x8 kf1 = *(const bf16x8*)(Kb + (size_t)(16 + n16) * 32 + G * 8);
  bf16x8 kf2 = *(const bf16x8*)(Kb + (size_t)(32 + n16) * 32 + G * 8);
  bf16x8 kf3 = *(const bf16x8*)(Kb + (size_t)(48 + n16) * 32 + G * 8);

  for (int it = 0; it < 32; ++it) {
    const f32x4 z = {0.f, 0.f, 0.f, 0.f};
    f32x4 S0[4], S1[4];
    S0[0] = MFMA(kf0, qf0, z); S1[0] = MFMA(kf0, qf1, z);
    S0[1] = MFMA(kf1, qf0, z); S1[1] = MFMA(kf1, qf1, z);
    S0[2] = MFMA(kf2, qf0, z); S1[2] = MFMA(kf2, qf1, z);
    S0[3] = MFMA(kf3, qf0, z); S1[3] = MFMA(kf3, qf1, z);

    {
      const u16* Kn = Kb + (size_t)(((it + 1) & 31) * 64) * 32;
      kf0 = *(const bf16x8*)(Kn + (size_t)n16 * 32 + G * 8);
      kf1 = *(const bf16x8*)(Kn + (size_t)(16 + n16) * 32 + G * 8);
      kf2 = *(const bf16x8*)(Kn + (size_t)(32 + n16) * 32 + G * 8);
      kf3 = *(const bf16x8*)(Kn + (size_t)(48 + n16) * 32 + G * 8);
    }

    float mt0 = fmaxf(fmaxf(S0[0].x, S0[0].y), fmaxf(S0[0].z, S0[0].w));
    float mt1 = fmaxf(fmaxf(S1[0].x, S1[0].y), fmaxf(S1[0].z, S1[0].w));
#pragma unroll
    for (int t = 1; t < 4; t++) {
      mt0 = fmaxf(mt0, fmaxf(fmaxf(S0[t].x, S0[t].y), fmaxf(S0[t].z, S0[t].w)));
      mt1 = fmaxf(mt1, fmaxf(fmaxf(S1[t].x, S1[t].y), fmaxf(S1[t].z, S1[t].w)));
    }
    mt0 = fmaxf(mt0, __shfl_xor(mt0, 16, 64));
    mt0 = fmaxf(mt0, __shfl_xor(mt0, 32, 64));
    mt1 = fmaxf(mt1, __shfl_xor(mt1, 16, 64));
    mt1 = fmaxf(mt1, __shfl_xor(mt1, 32, 64));
    float mn0 = fmaxf(m0, mt0), mn1 = fmaxf(m1, mt1);
    if (__any((mt0 > m0) | (mt1 > m1))) {
      float a0 = fexp2(m0 - mn0);
      float a1 = fexp2(m1 - mn1);
      l0 *= a0; l1 *= a1;
      O00 *= a0; O01 *= a0; O10 *= a1; O11 *= a1;
    }
    m0 = mn0; m1 = mn1;

#pragma unroll
    for (int t = 0; t < 4; t++) {
      float p0 = fexp2(S0[t].x - m0), p1 = fexp2(S0[t].y - m0);
      float p2 = fexp2(S0[t].z - m0), p3 = fexp2(S0[t].w - m0);
      l0 += (p0 + p1) + (p2 + p3);
      uint2 pr;
      pr.x = __builtin_amdgcn_perm(__float_as_uint(p1), __float_as_uint(p0), 0x07060302u);
      pr.y = __builtin_amdgcn_perm(__float_as_uint(p3), __float_as_uint(p2), 0x07060302u);
      *(uint2*)&Pw[n16 * 36 + 8 * t + 2 * G] = pr;
      float q0 = fexp2(S1[t].x - m1), q1 = fexp2(S1[t].y - m1);
      float q2 = fexp2(S1[t].z - m1), q3 = fexp2(S1[t].w - m1);
      l1 += (q0 + q1) + (q2 + q3);
      uint2 qr;
      qr.x = __builtin_amdgcn_perm(__float_as_uint(q1), __float_as_uint(q0), 0x07060302u);
      qr.y = __builtin_amdgcn_perm(__float_as_uint(q3), __float_as_uint(q2), 0x07060302u);
      *(uint2*)&Pw[(16 + n16) * 36 + 8 * t + 2 * G] = qr;
    }

#pragma unroll
    for (int c = 0; c < 2; c++) {
      const u16* Vp = Vb + (size_t)it * 64 + c * 32 + G * 8;
      bf16x8 va0 = *(const bf16x8*)(Vp + (size_t)n16 * 4096);
      bf16x8 va1 = *(const bf16x8*)(Vp + (size_t)(16 + n16) * 4096);
      union { uint4 u; bf16x8 v; } B0, B1;
      B0.u = *(uint4*)&Pw[n16 * 36 + 16 * c + 4 * G];
      B1.u = *(uint4*)&Pw[(16 + n16) * 36 + 16 * c + 4 * G];
      O00 = MFMA(va0, B0.v, O00);
      O01 = MFMA(va1, B0.v, O01);
      O10 = MFMA(va0, B1.v, O10);
      O11 = MFMA(va1, B1.v, O11);
    }
  }

  // merge m-split pairs (waves 2g / 2g+1) and store
  if (mh == 1) {
    float* dst = &MX[gq][lane][0];
    *(f32x4*)(dst + 0)  = O00;
    *(f32x4*)(dst + 4)  = O01;
    *(f32x4*)(dst + 8)  = O10;
    *(f32x4*)(dst + 12) = O11;
    dst[16] = m0; dst[17] = l0; dst[18] = m1; dst[19] = l1;
  }
  __syncthreads();
  if (mh == 0) {
    const float* src = &MX[gq][lane][0];
    f32x4 P00 = *(const f32x4*)(src + 0);
    f32x4 P01 = *(const f32x4*)(src + 4);
    f32x4 P10 = *(const f32x4*)(src + 8);
    f32x4 P11 = *(const f32x4*)(src + 12);
    float pm0 = src[16], pl0 = src[17], pm1 = src[18], pl1 = src[19];

    float M0 = fmaxf(m0, pm0);
    float se0 = fexp2(m0 - M0), so0 = fexp2(pm0 - M0);
    float M1 = fmaxf(m1, pm1);
    float se1 = fexp2(m1 - M1), so1 = fexp2(pm1 - M1);
    float ls0 = l0 * se0 + pl0 * so0;
    float ls1 = l1 * se1 + pl1 * so1;
    ls0 += __shfl_xor(ls0, 16, 64);
    ls0 += __shfl_xor(ls0, 32, 64);
    ls1 += __shfl_xor(ls1, 16, 64);
    ls1 += __shfl_xor(ls1, 32, 64);
    const float rl0 = 1.0f / ls0, rl1 = 1.0f / ls1;

    const int s0 = b * 4096 + qbase + n16;
    const int s1 = s0 + 16;
    const int cb0 = h * 2, cb1 = h * 2 + 1;
    u16 pk[4];
#pragma unroll
    for (int r = 0; r < 4; r++) pk[r] = f2bf((O00[r] * se0 + P00[r] * so0) * rl0);
    *(uint2*)(attnT + ((size_t)cb0 * 8192 + s0) * 16 + G * 4) = *(uint2*)pk;
#pragma unroll
    for (int r = 0; r < 4; r++) pk[r] = f2bf((O01[r] * se0 + P01[r] * so0) * rl0);
    *(uint2*)(attnT + ((size_t)cb1 * 8192 + s0) * 16 + G * 4) = *(uint2*)pk;
#pragma unroll
    for (int r = 0; r < 4; r++) pk[r] = f2bf((O10[r] * se1 + P10[r] * so1) * rl1);
    *(uint2*)(attnT + ((size_t)cb0 * 8192 + s1) * 16 + G * 4) = *(uint2*)pk;
#pragma unroll
    for (int r = 0; r < 4; r++) pk[r] = f2bf((O11[r] * se1 + P11[r] * so1) * rl1);
    *(uint2*)(attnT + ((size_t)cb1 * 8192 + s1) * 16 + G * 4) = *(uint2*)pk;
  }
}

// ---------------------------------------------------------------------------
// proj MFMA + BN (R7): wave = 32o x 32n, dual B-stream into one acc.
// ---------------------------------------------------------------------------
__global__ __launch_bounds__(256, 4) void proj_mfma_kernel(
    const u16* __restrict__ attnT, const u16* __restrict__ localT,
    const u16* __restrict__ wprojb,
    const float* __restrict__ g, const float* __restrict__ be,
    const float* __restrict__ mu, const float* __restrict__ var,
    float* __restrict__ out) {
  const int nB = blockIdx.x * 64;
  const int oB = blockIdx.y * 64;
  const int tid = threadIdx.x, lane = tid & 63, wv = tid >> 6;
  const int n16 = lane & 15, G = lane >> 4;
  const int waveO = oB + (wv >> 1) * 32;
  const int waveN = nB + (wv & 1) * 32;
  f32x4 acc[2][2] = {};
  const u16* Ap = wprojb + (size_t)(waveO + n16) * 256 + G * 8;
  const size_t boff = ((size_t)(G >> 1) * 8192 + waveN + n16) * 16 + (G & 1) * 8;
  for (int c0 = 0; c0 < 256; c0 += 32) {
    bf16x8 a0 = *(const bf16x8*)(Ap + c0);
    bf16x8 a1 = *(const bf16x8*)(Ap + 16 * 256 + c0);
    const size_t bo = boff + (size_t)(c0 >> 4) * 131072;
    bf16x8 p0 = *(const bf16x8*)(attnT + bo);
    bf16x8 p1 = *(const bf16x8*)(attnT + bo + 256);
    bf16x8 q0 = *(const bf16x8*)(localT + bo);
    bf16x8 q1 = *(const bf16x8*)(localT + bo + 256);
    acc[0][0] = MFMA(a0, p0, acc[0][0]);
    acc[0][1] = MFMA(a0, p1, acc[0][1]);
    acc[1][0] = MFMA(a1, p0, acc[1][0]);
    acc[1][1] = MFMA(a1, p1, acc[1][1]);
    acc[0][0] = MFMA(a0, q0, acc[0][0]);
    acc[0][1] = MFMA(a0, q1, acc[0][1]);
    acc[1][0] = MFMA(a1, q0, acc[1][0]);
    acc[1][1] = MFMA(a1, q1, acc[1][1]);
  }
#pragma unroll
  for (int i = 0; i < 2; i++) {
    int o0 = waveO + i * 16 + G * 4;
    float inv[4], sh[4];
#pragma unroll
    for (int r = 0; r < 4; r++) {
      int o = o0 + r;
      float iv = g[o] * rsqrtf(var[o] + EPSV);
      inv[r] = iv; sh[r] = be[o] - mu[o] * iv;
    }
#pragma unroll
    for (int j = 0; j < 2; j++) {
      int s = waveN + j * 16 + n16;
      int b = s >> 12, n = s & 4095;
      float* op = out + ((size_t)(b * 256 + o0)) * 4096 + n;
#pragma unroll
      for (int r = 0; r < 4; r++) op[(size_t)r * 4096] = acc[i][j][r] * inv[r] + sh[r];
    }
  }
}

extern "C" void kernel_launch(void* const* d_in, const int* in_sizes, int n_in,
                              void* d_out, int out_size, void* d_ws, size_t ws_size,
                              hipStream_t stream) {
  (void)in_sizes; (void)n_in; (void)out_size; (void)ws_size;
  const float* x       = (const float*)d_in[0];
  const float* w_qkv   = (const float*)d_in[1];
  const float* w_local = (const float*)d_in[2];
  const float* lg = (const float*)d_in[3];
  const float* lb = (const float*)d_in[4];
  const float* lm = (const float*)d_in[5];
  const float* lv = (const float*)d_in[6];
  const float* w_proj  = (const float*)d_in[7];
  const float* pg = (const float*)d_in[8];
  const float* pb = (const float*)d_in[9];
  const float* pm = (const float*)d_in[10];
  const float* pvr = (const float*)d_in[11];
  float* out = (float*)d_out;

  // ws layout (u16 units)
  u16* Q      = (u16*)d_ws;          // 2M
  u16* K      = Q + 2097152;         // 2M
  u16* Vt     = K + 2097152;         // 2M
  u16* xT     = Vt + 2097152;        // 2M
  u16* attnT  = xT + 2097152;        // 2M
  u16* localT = attnT + 2097152;     // 2M
  u16* wqkvb  = localT + 2097152;    // 196608
  u16* wprojb = wqkvb + 196608;      // 65536
  u16* wb     = wprojb + 65536;      // 589824

  hipLaunchKernelGGL(prep_kernel, dim3(1792), dim3(256), 0, stream,
                     x, w_qkv, w_proj, w_local, xT, wqkvb, wprojb, wb);
  hipLaunchKernelGGL(qkv_kernel, dim3(768), dim3(256), 0, stream,
                     xT, wqkvb, Q, K, Vt);
  hipLaunchKernelGGL(flashconv_kernel, dim3(1536), dim3(256), 0, stream,
                     Q, K, Vt, attnT, xT, wb, lg, lb, lm, lv, localT);
  hipLaunchKernelGGL(proj_mfma_kernel, dim3(128, 4), dim3(256), 0, stream,
                     attnT, localT, wprojb, pg, pb, pm, pvr, out);
}

// Round 12
// 235.202 us; speedup vs baseline: 1.4885x; 1.1045x over previous
//
#include <hip/hip_runtime.h>

#define EPSV 1e-5f

typedef unsigned short u16;
typedef unsigned int u32;
typedef __attribute__((ext_vector_type(8))) short bf16x8;
typedef __attribute__((ext_vector_type(4))) float f32x4;

__device__ __forceinline__ u16 f2bf(float f) {
  u32 u = __float_as_uint(f);
  u32 r = (u + 0x7FFFu + ((u >> 16) & 1u)) >> 16;
  return (u16)r;
}
__device__ __forceinline__ float fexp2(float x) {
  float r;
  asm("v_exp_f32 %0, %1" : "=v"(r) : "v"(x));
  return r;
}

#define MFMA(a, b, c) __builtin_amdgcn_mfma_f32_16x16x32_bf16((a), (b), (c), 0, 0, 0)

// ---------------------------------------------------------------------------
// prep (fused): blocks 0..511 transpose x -> xT bf16 [(c>>4)][s][c&15];
// blocks 512..1791 cast weights (QSCALE*log2e folded into Wq rows).
// ---------------------------------------------------------------------------
__global__ __launch_bounds__(256) void prep_kernel(
    const float* __restrict__ x, const float* __restrict__ wqkv,
    const float* __restrict__ wproj, const float* __restrict__ wloc,
    u16* __restrict__ xT, u16* __restrict__ wqkvb,
    u16* __restrict__ wprojb, u16* __restrict__ wb) {
  __shared__ float Ls[16][260];
  const int bid = blockIdx.x;
  const int tid = threadIdx.x;
  if (bid < 512) {
    const int nt = bid & 15, cb = (bid >> 4) & 15, b = bid >> 8;
    const int cc0 = tid >> 6, n4 = (tid & 63) * 4;
    const float* xb = x + ((size_t)(b * 256 + cb * 16)) * 4096 + nt * 256;
#pragma unroll
    for (int j = 0; j < 4; j++) {
      int cc = j * 4 + cc0;
      *(float4*)&Ls[cc][n4] = *(const float4*)(xb + (size_t)cc * 4096 + n4);
    }
    __syncthreads();
    const int n = tid;
    u16 buf[16];
#pragma unroll
    for (int c = 0; c < 16; c++) buf[c] = f2bf(Ls[c][n]);
    u16* dst = xT + ((size_t)cb * 8192 + b * 4096 + nt * 256 + n) * 16;
    *(uint4*)(dst) = *(uint4*)&buf[0];
    *(uint4*)(dst + 8) = *(uint4*)&buf[8];
  } else {
    const int r = bid - 512, c = tid;
    const float QSCALE = 0.17677669529663687f * 1.4426950408889634f;
    if (r < 768) {
      float sc = (r < 256) ? QSCALE : 1.0f;
      wqkvb[r * 256 + c] = f2bf(wqkv[r * 256 + c] * sc);
    } else if (r < 1024) {
      int o = r - 768;
      wprojb[o * 256 + c] = f2bf(wproj[o * 256 + c]);
    } else {
      int o = r - 1024;
      const float* src = wloc + ((size_t)o * 256 + c) * 9;
#pragma unroll
      for (int tap = 0; tap < 9; tap++)
        wb[tap * 65536 + o * 256 + c] = f2bf(src[tap]);
    }
  }
}

// ---------------------------------------------------------------------------
// qkvconv (R7-exact): blocks 0..767 = qkv GEMM (wave 32o x 64n),
// blocks 768..1279 = conv3x3+BN (wave 32o x 32n). Direct-from-L2, no LDS.
// ---------------------------------------------------------------------------
__global__ __launch_bounds__(256, 4) void qkvconv_kernel(
    const u16* __restrict__ xT, const u16* __restrict__ wqkvb,
    const u16* __restrict__ wb,
    const float* __restrict__ g, const float* __restrict__ be,
    const float* __restrict__ mu, const float* __restrict__ var,
    u16* __restrict__ Qg, u16* __restrict__ Kg, u16* __restrict__ Vtg,
    u16* __restrict__ localT) {
  const int bid = blockIdx.x;
  const int tid = threadIdx.x, lane = tid & 63, wv = tid >> 6;
  const int n16 = lane & 15, G = lane >> 4;
  if (bid < 768) {
    const int nB = (bid & 63) * 128;
    const int oB = (bid >> 6) * 64;
    const int waveO = oB + (wv >> 1) * 32;
    const int waveN = nB + (wv & 1) * 64;
    f32x4 acc[2][4] = {};
    const u16* Ap = wqkvb + (size_t)(waveO + n16) * 256 + G * 8;
    const u16* Bp = xT + ((size_t)(G >> 1) * 8192 + waveN + n16) * 16 + (G & 1) * 8;
    for (int c0 = 0; c0 < 256; c0 += 32) {
      bf16x8 a0 = *(const bf16x8*)(Ap + c0);
      bf16x8 a1 = *(const bf16x8*)(Ap + 16 * 256 + c0);
      const u16* bp = Bp + (size_t)(c0 >> 4) * 131072;
      bf16x8 b0 = *(const bf16x8*)(bp);
      bf16x8 b1 = *(const bf16x8*)(bp + 256);
      bf16x8 b2 = *(const bf16x8*)(bp + 512);
      bf16x8 b3 = *(const bf16x8*)(bp + 768);
      acc[0][0] = MFMA(a0, b0, acc[0][0]);
      acc[0][1] = MFMA(a0, b1, acc[0][1]);
      acc[0][2] = MFMA(a0, b2, acc[0][2]);
      acc[0][3] = MFMA(a0, b3, acc[0][3]);
      acc[1][0] = MFMA(a1, b0, acc[1][0]);
      acc[1][1] = MFMA(a1, b1, acc[1][1]);
      acc[1][2] = MFMA(a1, b2, acc[1][2]);
      acc[1][3] = MFMA(a1, b3, acc[1][3]);
    }
    const int which = oB >> 8;
    if (which < 2) {
      u16* base = which ? Kg : Qg;
#pragma unroll
      for (int i = 0; i < 2; i++) {
        int o0 = waveO + i * 16 + G * 4;
        int h = (o0 >> 5) & 7, d0 = o0 & 31;
#pragma unroll
        for (int j = 0; j < 4; j++) {
          int s = waveN + j * 16 + n16;
          int b = s >> 12, n = s & 4095;
          u16 pk[4];
#pragma unroll
          for (int r = 0; r < 4; r++) pk[r] = f2bf(acc[i][j][r]);
          *(uint2*)(base + ((size_t)(b * 8 + h) * 4096 + n) * 32 + d0) = *(uint2*)pk;
        }
      }
    } else {
#pragma unroll
      for (int i = 0; i < 2; i++) {
        int o0 = waveO + i * 16 + G * 4;
        int h = (o0 >> 5) & 7, d0 = o0 & 31;
#pragma unroll
        for (int j = 0; j < 4; j++) {
          int s = waveN + j * 16 + n16;
          int b = s >> 12, n = s & 4095;
          u16* vp = Vtg + ((size_t)(b * 8 + h) * 32 + d0) * 4096 + n;
#pragma unroll
          for (int r = 0; r < 4; r++) vp[(size_t)r * 4096] = f2bf(acc[i][j][r]);
        }
      }
    }
  } else {
    const int r0 = bid - 768;
    const int nB = (r0 & 127) * 64;
    const int oB = (r0 >> 7) * 64;
    const int waveO = oB + (wv >> 1) * 32;
    const int waveN = nB + (wv & 1) * 32;
    const int y = (nB >> 6) & 63;
    const int x0 = waveN & 63;
    f32x4 acc[2][2] = {};
    const u16* Ap = wb + (size_t)(waveO + n16) * 256 + G * 8;
    const u16* Bp = xT + ((size_t)(G >> 1) * 8192 + waveN + n16) * 16 + (G & 1) * 8;
    const bf16x8 z = {0, 0, 0, 0, 0, 0, 0, 0};
    for (int c0 = 0; c0 < 256; c0 += 32) {
      const u16* bp = Bp + (size_t)(c0 >> 4) * 131072;
      const u16* ap = Ap + c0;
#pragma unroll
      for (int tap = 0; tap < 9; tap++) {
        const int dy = tap / 3 - 1, dx = tap % 3 - 1;
        int yy = y + dy;
        if ((unsigned)yy >= 64u) continue;
        bf16x8 a0 = *(const bf16x8*)(ap + (size_t)tap * 65536);
        bf16x8 a1 = *(const bf16x8*)(ap + (size_t)tap * 65536 + 16 * 256);
        const int off = dy * 64 + dx;
        bf16x8 b0, b1;
        if (dx == 0) {
          b0 = *(const bf16x8*)(bp + (ptrdiff_t)off * 16);
          b1 = *(const bf16x8*)(bp + (ptrdiff_t)(off + 16) * 16);
        } else {
          bool v0 = (unsigned)(x0 + n16 + dx) < 64u;
          bool v1 = (unsigned)(x0 + 16 + n16 + dx) < 64u;
          int o0 = v0 ? off : 0;
          int o1 = v1 ? (off + 16) : 16;
          bf16x8 t0 = *(const bf16x8*)(bp + (ptrdiff_t)o0 * 16);
          bf16x8 t1 = *(const bf16x8*)(bp + (ptrdiff_t)o1 * 16);
          b0 = v0 ? t0 : z;
          b1 = v1 ? t1 : z;
        }
        acc[0][0] = MFMA(a0, b0, acc[0][0]);
        acc[0][1] = MFMA(a0, b1, acc[0][1]);
        acc[1][0] = MFMA(a1, b0, acc[1][0]);
        acc[1][1] = MFMA(a1, b1, acc[1][1]);
      }
    }
#pragma unroll
    for (int i = 0; i < 2; i++) {
      int o0 = waveO + i * 16 + G * 4;
      float inv[4], sh[4];
#pragma unroll
      for (int r = 0; r < 4; r++) {
        int o = o0 + r;
        float iv = g[o] * rsqrtf(var[o] + EPSV);
        inv[r] = iv; sh[r] = be[o] - mu[o] * iv;
      }
#pragma unroll
      for (int j = 0; j < 2; j++) {
        int s = waveN + j * 16 + n16;
        u16 pk[4];
#pragma unroll
        for (int r = 0; r < 4; r++) pk[r] = f2bf(acc[i][j][r] * inv[r] + sh[r]);
        *(uint2*)(localT + ((size_t)(o0 >> 4) * 8192 + s) * 16 + (o0 & 15)) = *(uint2*)pk;
      }
    }
  }
}

// ---------------------------------------------------------------------------
// flash: m-split 4, grid 2048, __launch_bounds__(256,4) (proven no-spill).
// Block = 4 waves on one 32-q group; wave w covers m [w*1024,+1024).
// LDS = Ps only (18432 B, MX overlaid) -> HW residency up to 8 blocks/CU at
// ~60 VGPR (launch_bounds is an allocator floor, not an occupancy cap).
// Max-tracked softmax (proven), per-lane l partials, K prefetch,
// LEAN 4-way merge (scale-in-place, no A-temps -- the R8-R10 spill source).
// ---------------------------------------------------------------------------
__global__ __launch_bounds__(256, 4) void flash_mfma_kernel(
    const u16* __restrict__ Qg, const u16* __restrict__ Kg,
    const u16* __restrict__ Vtg, u16* __restrict__ attnT) {
  __shared__ u32 SMEM[4608];          // 18432 B: Ps (4x1152) overlaid by MX
  const int bid = blockIdx.x;
  const int bh = bid >> 7, qt = bid & 127;
  const int tid = threadIdx.x, lane = tid & 63, w = tid >> 6;
  const int n16 = lane & 15, G = lane >> 4;
  const int b = bh >> 3, h = bh & 7;
  const int qbase = qt * 32;

  const u16* Qp = Qg + ((size_t)bh * 4096 + qbase) * 32;
  const bf16x8 qf0 = *(const bf16x8*)(Qp + (size_t)n16 * 32 + G * 8);
  const bf16x8 qf1 = *(const bf16x8*)(Qp + (size_t)(16 + n16) * 32 + G * 8);

  f32x4 O00 = {0.f,0.f,0.f,0.f}, O01 = {0.f,0.f,0.f,0.f};
  f32x4 O10 = {0.f,0.f,0.f,0.f}, O11 = {0.f,0.f,0.f,0.f};
  float m0 = -3.0e38f, m1 = -3.0e38f, l0 = 0.f, l1 = 0.f;

  const u16* Kb = Kg + ((size_t)bh * 4096 + w * 1024) * 32;
  const u16* Vb = Vtg + (size_t)bh * 32 * 4096 + w * 1024;
  u32* Pw = SMEM + w * 1152;

  bf16x8 kf0 = *(const bf16x8*)(Kb + (size_t)n16 * 32 + G * 8);
  bf16x8 kf1 = *(const bf16x8*)(Kb + (size_t)(16 + n16) * 32 + G * 8);
  bf16x8 kf2 = *(const bf16x8*)(Kb + (size_t)(32 + n16) * 32 + G * 8);
  bf16x8 kf3 = *(const bf16x8*)(Kb + (size_t)(48 + n16) * 32 + G * 8);

  for (int it = 0; it < 16; ++it) {
    const f32x4 z = {0.f, 0.f, 0.f, 0.f};
    f32x4 S0[4], S1[4];
    S0[0] = MFMA(kf0, qf0, z); S1[0] = MFMA(kf0, qf1, z);
    S0[1] = MFMA(kf1, qf0, z); S1[1] = MFMA(kf1, qf1, z);
    S0[2] = MFMA(kf2, qf0, z); S1[2] = MFMA(kf2, qf1, z);
    S0[3] = MFMA(kf3, qf0, z); S1[3] = MFMA(kf3, qf1, z);

    {
      const u16* Kn = Kb + (size_t)(((it + 1) & 15) * 64) * 32;
      kf0 = *(const bf16x8*)(Kn + (size_t)n16 * 32 + G * 8);
      kf1 = *(const bf16x8*)(Kn + (size_t)(16 + n16) * 32 + G * 8);
      kf2 = *(const bf16x8*)(Kn + (size_t)(32 + n16) * 32 + G * 8);
      kf3 = *(const bf16x8*)(Kn + (size_t)(48 + n16) * 32 + G * 8);
    }

    float mt0 = fmaxf(fmaxf(S0[0].x, S0[0].y), fmaxf(S0[0].z, S0[0].w));
    float mt1 = fmaxf(fmaxf(S1[0].x, S1[0].y), fmaxf(S1[0].z, S1[0].w));
#pragma unroll
    for (int t = 1; t < 4; t++) {
      mt0 = fmaxf(mt0, fmaxf(fmaxf(S0[t].x, S0[t].y), fmaxf(S0[t].z, S0[t].w)));
      mt1 = fmaxf(mt1, fmaxf(fmaxf(S1[t].x, S1[t].y), fmaxf(S1[t].z, S1[t].w)));
    }
    mt0 = fmaxf(mt0, __shfl_xor(mt0, 16, 64));
    mt0 = fmaxf(mt0, __shfl_xor(mt0, 32, 64));
    mt1 = fmaxf(mt1, __shfl_xor(mt1, 16, 64));
    mt1 = fmaxf(mt1, __shfl_xor(mt1, 32, 64));
    float mn0 = fmaxf(m0, mt0), mn1 = fmaxf(m1, mt1);
    if (__any((mt0 > m0) | (mt1 > m1))) {
      float a0 = fexp2(m0 - mn0);
      float a1 = fexp2(m1 - mn1);
      l0 *= a0; l1 *= a1;
      O00 *= a0; O01 *= a0; O10 *= a1; O11 *= a1;
    }
    m0 = mn0; m1 = mn1;

#pragma unroll
    for (int t = 0; t < 4; t++) {
      float p0 = fexp2(S0[t].x - m0), p1 = fexp2(S0[t].y - m0);
      float p2 = fexp2(S0[t].z - m0), p3 = fexp2(S0[t].w - m0);
      l0 += (p0 + p1) + (p2 + p3);
      uint2 pr;
      pr.x = __builtin_amdgcn_perm(__float_as_uint(p1), __float_as_uint(p0), 0x07060302u);
      pr.y = __builtin_amdgcn_perm(__float_as_uint(p3), __float_as_uint(p2), 0x07060302u);
      *(uint2*)&Pw[n16 * 36 + 8 * t + 2 * G] = pr;
      float q0 = fexp2(S1[t].x - m1), q1 = fexp2(S1[t].y - m1);
      float q2 = fexp2(S1[t].z - m1), q3 = fexp2(S1[t].w - m1);
      l1 += (q0 + q1) + (q2 + q3);
      uint2 qr;
      qr.x = __builtin_amdgcn_perm(__float_as_uint(q1), __float_as_uint(q0), 0x07060302u);
      qr.y = __builtin_amdgcn_perm(__float_as_uint(q3), __float_as_uint(q2), 0x07060302u);
      *(uint2*)&Pw[(16 + n16) * 36 + 8 * t + 2 * G] = qr;
    }

#pragma unroll
    for (int c = 0; c < 2; c++) {
      const u16* Vp = Vb + (size_t)it * 64 + c * 32 + G * 8;
      bf16x8 va0 = *(const bf16x8*)(Vp + (size_t)n16 * 4096);
      bf16x8 va1 = *(const bf16x8*)(Vp + (size_t)(16 + n16) * 4096);
      union { uint4 u; bf16x8 v; } B0, B1;
      B0.u = *(uint4*)&Pw[n16 * 36 + 16 * c + 4 * G];
      B1.u = *(uint4*)&Pw[(16 + n16) * 36 + 16 * c + 4 * G];
      O00 = MFMA(va0, B0.v, O00);
      O01 = MFMA(va1, B0.v, O01);
      O10 = MFMA(va0, B1.v, O10);
      O11 = MFMA(va1, B1.v, O11);
    }
  }

  // -------- lean 4-way merge (MX overlays Ps) --------
  __syncthreads();
  float* MXf = (float*)SMEM;
  if (w > 0) {
    float* dst = MXf + ((size_t)(w - 1) * 64 + lane) * 20;
    *(f32x4*)(dst + 0)  = O00;
    *(f32x4*)(dst + 4)  = O01;
    *(f32x4*)(dst + 8)  = O10;
    *(f32x4*)(dst + 12) = O11;
    dst[16] = m0; dst[17] = l0; dst[18] = m1; dst[19] = l1;
  }
  __syncthreads();
  if (w == 0) {
    float M0 = m0, M1 = m1;
#pragma unroll
    for (int ww = 0; ww < 3; ww++) {
      const float* src = MXf + ((size_t)ww * 64 + lane) * 20;
      M0 = fmaxf(M0, src[16]);
      M1 = fmaxf(M1, src[18]);
    }
    {
      float se0 = fexp2(m0 - M0), se1 = fexp2(m1 - M1);
      O00 *= se0; O01 *= se0; O10 *= se1; O11 *= se1;
      l0 *= se0; l1 *= se1;
    }
#pragma unroll
    for (int ww = 0; ww < 3; ww++) {
      const float* src = MXf + ((size_t)ww * 64 + lane) * 20;
      float s0 = fexp2(src[16] - M0), s1 = fexp2(src[18] - M1);
      O00 += *(const f32x4*)(src + 0) * s0;
      O01 += *(const f32x4*)(src + 4) * s0;
      O10 += *(const f32x4*)(src + 8) * s1;
      O11 += *(const f32x4*)(src + 12) * s1;
      l0 += src[17] * s0;
      l1 += src[19] * s1;
    }
    l0 += __shfl_xor(l0, 16, 64);
    l0 += __shfl_xor(l0, 32, 64);
    l1 += __shfl_xor(l1, 16, 64);
    l1 += __shfl_xor(l1, 32, 64);
    const float rl0 = 1.0f / l0, rl1 = 1.0f / l1;
    const int s0i = b * 4096 + qbase + n16;
    const int s1i = s0i + 16;
    const int cb0 = h * 2, cb1 = h * 2 + 1;
    u16 pk[4];
#pragma unroll
    for (int r = 0; r < 4; r++) pk[r] = f2bf(O00[r] * rl0);
    *(uint2*)(attnT + ((size_t)cb0 * 8192 + s0i) * 16 + G * 4) = *(uint2*)pk;
#pragma unroll
    for (int r = 0; r < 4; r++) pk[r] = f2bf(O01[r] * rl0);
    *(uint2*)(attnT + ((size_t)cb1 * 8192 + s0i) * 16 + G * 4) = *(uint2*)pk;
#pragma unroll
    for (int r = 0; r < 4; r++) pk[r] = f2bf(O10[r] * rl1);
    *(uint2*)(attnT + ((size_t)cb0 * 8192 + s1i) * 16 + G * 4) = *(uint2*)pk;
#pragma unroll
    for (int r = 0; r < 4; r++) pk[r] = f2bf(O11[r] * rl1);
    *(uint2*)(attnT + ((size_t)cb1 * 8192 + s1i) * 16 + G * 4) = *(uint2*)pk;
  }
}

// ---------------------------------------------------------------------------
// proj MFMA + BN (R7): wave = 32o x 32n, dual B-stream into one acc.
// ---------------------------------------------------------------------------
__global__ __launch_bounds__(256, 4) void proj_mfma_kernel(
    const u16* __restrict__ attnT, const u16* __restrict__ localT,
    const u16* __restrict__ wprojb,
    const float* __restrict__ g, const float* __restrict__ be,
    const float* __restrict__ mu, const float* __restrict__ var,
    float* __restrict__ out) {
  const int nB = blockIdx.x * 64;
  const int oB = blockIdx.y * 64;
  const int tid = threadIdx.x, lane = tid & 63, wv = tid >> 6;
  const int n16 = lane & 15, G = lane >> 4;
  const int waveO = oB + (wv >> 1) * 32;
  const int waveN = nB + (wv & 1) * 32;
  f32x4 acc[2][2] = {};
  const u16* Ap = wprojb + (size_t)(waveO + n16) * 256 + G * 8;
  const size_t boff = ((size_t)(G >> 1) * 8192 + waveN + n16) * 16 + (G & 1) * 8;
  for (int c0 = 0; c0 < 256; c0 += 32) {
    bf16x8 a0 = *(const bf16x8*)(Ap + c0);
    bf16x8 a1 = *(const bf16x8*)(Ap + 16 * 256 + c0);
    const size_t bo = boff + (size_t)(c0 >> 4) * 131072;
    bf16x8 p0 = *(const bf16x8*)(attnT + bo);
    bf16x8 p1 = *(const bf16x8*)(attnT + bo + 256);
    bf16x8 q0 = *(const bf16x8*)(localT + bo);
    bf16x8 q1 = *(const bf16x8*)(localT + bo + 256);
    acc[0][0] = MFMA(a0, p0, acc[0][0]);
    acc[0][1] = MFMA(a0, p1, acc[0][1]);
    acc[1][0] = MFMA(a1, p0, acc[1][0]);
    acc[1][1] = MFMA(a1, p1, acc[1][1]);
    acc[0][0] = MFMA(a0, q0, acc[0][0]);
    acc[0][1] = MFMA(a0, q1, acc[0][1]);
    acc[1][0] = MFMA(a1, q0, acc[1][0]);
    acc[1][1] = MFMA(a1, q1, acc[1][1]);
  }
#pragma unroll
  for (int i = 0; i < 2; i++) {
    int o0 = waveO + i * 16 + G * 4;
    float inv[4], sh[4];
#pragma unroll
    for (int r = 0; r < 4; r++) {
      int o = o0 + r;
      float iv = g[o] * rsqrtf(var[o] + EPSV);
      inv[r] = iv; sh[r] = be[o] - mu[o] * iv;
    }
#pragma unroll
    for (int j = 0; j < 2; j++) {
      int s = waveN + j * 16 + n16;
      int b = s >> 12, n = s & 4095;
      float* op = out + ((size_t)(b * 256 + o0)) * 4096 + n;
#pragma unroll
      for (int r = 0; r < 4; r++) op[(size_t)r * 4096] = acc[i][j][r] * inv[r] + sh[r];
    }
  }
}

extern "C" void kernel_launch(void* const* d_in, const int* in_sizes, int n_in,
                              void* d_out, int out_size, void* d_ws, size_t ws_size,
                              hipStream_t stream) {
  (void)in_sizes; (void)n_in; (void)out_size; (void)ws_size;
  const float* x       = (const float*)d_in[0];
  const float* w_qkv   = (const float*)d_in[1];
  const float* w_local = (const float*)d_in[2];
  const float* lg = (const float*)d_in[3];
  const float* lb = (const float*)d_in[4];
  const float* lm = (const float*)d_in[5];
  const float* lv = (const float*)d_in[6];
  const float* w_proj  = (const float*)d_in[7];
  const float* pg = (const float*)d_in[8];
  const float* pb = (const float*)d_in[9];
  const float* pm = (const float*)d_in[10];
  const float* pvr = (const float*)d_in[11];
  float* out = (float*)d_out;

  // ws layout (u16 units)
  u16* Q      = (u16*)d_ws;          // 2M
  u16* K      = Q + 2097152;         // 2M
  u16* Vt     = K + 2097152;         // 2M
  u16* xT     = Vt + 2097152;        // 2M
  u16* attnT  = xT + 2097152;        // 2M
  u16* localT = attnT + 2097152;     // 2M
  u16* wqkvb  = localT + 2097152;    // 196608
  u16* wprojb = wqkvb + 196608;      // 65536
  u16* wb     = wprojb + 65536;      // 589824

  hipLaunchKernelGGL(prep_kernel, dim3(1792), dim3(256), 0, stream,
                     x, w_qkv, w_proj, w_local, xT, wqkvb, wprojb, wb);
  hipLaunchKernelGGL(qkvconv_kernel, dim3(1280), dim3(256), 0, stream,
                     xT, wqkvb, wb, lg, lb, lm, lv, Q, K, Vt, localT);
  hipLaunchKernelGGL(flash_mfma_kernel, dim3(2048), dim3(256), 0, stream,
                     Q, K, Vt, attnT);
  hipLaunchKernelGGL(proj_mfma_kernel, dim3(128, 4), dim3(256), 0, stream,
                     attnT, localT, wprojb, pg, pb, pm, pvr, out);
}